// Round 1
// baseline (449.626 us; speedup 1.0000x reference)
//
#include <hip/hip_runtime.h>
#include <hip/hip_bf16.h>

// Problem constants (L,N,E,H,D) = (2048,4,512,8,64)
#define E_DIM 512
#define N_BATCH 4
#define L_SEQ 2048
#define N_HEADS 8
#define H_DIM 64
#define N_ROWS (L_SEQ * N_BATCH) /* 8192 */
#define EPS_F 1e-6f
#define SC_Q 0.18033688f  /* 0.125 * log2(e): scores come out in log2 space */

typedef __attribute__((ext_vector_type(8))) short bf16x8;
typedef __attribute__((ext_vector_type(8))) _Float16 f16x8;
typedef __attribute__((ext_vector_type(4))) float f32x4;
typedef __attribute__((ext_vector_type(16))) float f32x16;

__device__ __forceinline__ void split2(float f, __hip_bfloat16& h, __hip_bfloat16& l) {
  h = __float2bfloat16(f);
  l = __float2bfloat16(f - __bfloat162float(h));
}

__device__ __forceinline__ unsigned int packf16(float a, float b) {
  union { _Float16 h[2]; unsigned int u; } c;
  c.h[0] = (_Float16)a;  // RN casts: unbiased (RTZ pkrtz would bias softmax weights)
  c.h[1] = (_Float16)b;
  return c.u;
}

// ---------------------------------------------------------------------------
// Kernel W: pre-split weights fp32 -> bf16 hi/lo.  (wiolo now unused by proj
// but kept for layout stability; wohi/wolo feed out_proj.)
// ---------------------------------------------------------------------------
__global__ __launch_bounds__(256) void wconv_kernel(
    const float* __restrict__ wio, const float* __restrict__ wo,
    __hip_bfloat16* __restrict__ wiohi, __hip_bfloat16* __restrict__ wiolo,
    __hip_bfloat16* __restrict__ wohi, __hip_bfloat16* __restrict__ wolo) {
  const int g = blockIdx.x * 256 + threadIdx.x;
  const float* src;
  __hip_bfloat16 *dh, *dl;
  int i;
  if (g < 196608) { src = wio; dh = wiohi; dl = wiolo; i = g * 4; }
  else            { src = wo;  dh = wohi;  dl = wolo;  i = (g - 196608) * 4; }
  const float4 f = *(const float4*)(src + i);
  alignas(8) __hip_bfloat16 h[4], l[4];
  split2(f.x, h[0], l[0]); split2(f.y, h[1], l[1]);
  split2(f.z, h[2], l[2]); split2(f.w, h[3], l[3]);
  *(uint2*)(dh + i) = *(const uint2*)h;
  *(uint2*)(dl + i) = *(const uint2*)l;
}

// ---------------------------------------------------------------------------
// Kernel A: packed QKV projection via MFMA, hi/lo 2-pass (hh + lh; the hl
// term x_hi*w_lo is dropped -- its ~6e-4 q/k/v error attenuates to ~2e-5
// through attention).  Q epilogue folds the 0.125*log2e softmax scale and
// stores fp16; K stores fp16; V stores u = max(v+sh,eps)^p fp32.
// ---------------------------------------------------------------------------
__global__ __launch_bounds__(256, 3) void proj_qkv_kernel(
    const float* __restrict__ xq, const float* __restrict__ xk,
    const float* __restrict__ xv, const __hip_bfloat16* __restrict__ whi,
    const float* __restrict__ bias, const float* __restrict__ pw,
    const float* __restrict__ sw,
    _Float16* __restrict__ qbuf, _Float16* __restrict__ kbuf,
    float* __restrict__ ubuf) {
  __shared__ __hip_bfloat16 Xh[128][40];
  __shared__ __hip_bfloat16 Xl[128][40];
  __shared__ __hip_bfloat16 Wh[128][40];
  const int z = blockIdx.z;
  const int row0 = blockIdx.x * 128;
  const int col0 = blockIdx.y * 128;
  const float* __restrict__ xsrc = (z == 0) ? xq : (z == 1) ? xk : xv;
  const int tid = threadIdx.x;
  const int lane = tid & 63;
  const int wv = tid >> 6;
  const int lidx = lane & 15;
  const int quad = lane >> 4;
  const int srow = tid >> 1;
  const int scol = (tid & 1) * 16;

  f32x4 acc[2][8];
#pragma unroll
  for (int rt = 0; rt < 2; ++rt)
#pragma unroll
    for (int ct = 0; ct < 8; ++ct) acc[rt][ct] = (f32x4){0.f, 0.f, 0.f, 0.f};

  const int ar0 = wv * 32 + lidx;

  for (int kt = 0; kt < 16; ++kt) {
    const int k0 = kt * 32;
    {
      const float* xp = xsrc + (size_t)(row0 + srow) * E_DIM + k0 + scol;
      float f[16];
      *(float4*)&f[0]  = ((const float4*)xp)[0];
      *(float4*)&f[4]  = ((const float4*)xp)[1];
      *(float4*)&f[8]  = ((const float4*)xp)[2];
      *(float4*)&f[12] = ((const float4*)xp)[3];
      alignas(16) __hip_bfloat16 hi[16], lo[16];
#pragma unroll
      for (int j = 0; j < 16; ++j) split2(f[j], hi[j], lo[j]);
      *(uint4*)&Xh[srow][scol]     = ((const uint4*)hi)[0];
      *(uint4*)&Xh[srow][scol + 8] = ((const uint4*)hi)[1];
      *(uint4*)&Xl[srow][scol]     = ((const uint4*)lo)[0];
      *(uint4*)&Xl[srow][scol + 8] = ((const uint4*)lo)[1];
    }
    {
      const size_t wof = (size_t)(z * E_DIM + col0 + srow) * E_DIM + k0 + scol;
      *(uint4*)&Wh[srow][scol]     = ((const uint4*)(whi + wof))[0];
      *(uint4*)&Wh[srow][scol + 8] = ((const uint4*)(whi + wof))[1];
    }
    __syncthreads();

    const bf16x8 ah0 = *(const bf16x8*)&Xh[ar0][quad * 8];
    const bf16x8 ah1 = *(const bf16x8*)&Xh[ar0 + 16][quad * 8];
    const bf16x8 al0 = *(const bf16x8*)&Xl[ar0][quad * 8];
    const bf16x8 al1 = *(const bf16x8*)&Xl[ar0 + 16][quad * 8];
#pragma unroll
    for (int ct = 0; ct < 8; ++ct) {
      const bf16x8 bh = *(const bf16x8*)&Wh[ct * 16 + lidx][quad * 8];
      acc[0][ct] = __builtin_amdgcn_mfma_f32_16x16x32_bf16(ah0, bh, acc[0][ct], 0, 0, 0);
      acc[0][ct] = __builtin_amdgcn_mfma_f32_16x16x32_bf16(al0, bh, acc[0][ct], 0, 0, 0);
      acc[1][ct] = __builtin_amdgcn_mfma_f32_16x16x32_bf16(ah1, bh, acc[1][ct], 0, 0, 0);
      acc[1][ct] = __builtin_amdgcn_mfma_f32_16x16x32_bf16(al1, bh, acc[1][ct], 0, 0, 0);
    }
    __syncthreads();
  }

  if (z < 2) {
    _Float16* __restrict__ dst = (z == 0) ? qbuf : kbuf;
    const float scale = (z == 0) ? SC_Q : 1.0f;
    float bv[8];
#pragma unroll
    for (int ct = 0; ct < 8; ++ct) bv[ct] = bias[z * E_DIM + col0 + ct * 16 + lidx];
#pragma unroll
    for (int rt = 0; rt < 2; ++rt)
#pragma unroll
      for (int ct = 0; ct < 8; ++ct) {
        const int e = col0 + ct * 16 + lidx;
        const int h = e >> 6, d = e & 63;
#pragma unroll
        for (int reg = 0; reg < 4; ++reg) {
          const int R = row0 + wv * 32 + rt * 16 + quad * 4 + reg;
          const int lpos = R >> 2, nb = R & 3;
          dst[(((size_t)nb * N_HEADS + h) * L_SEQ + lpos) * H_DIM + d] =
              (_Float16)((acc[rt][ct][reg] + bv[ct]) * scale);
        }
      }
  } else {
    float bv[8], pv[8], sv[8];
#pragma unroll
    for (int ct = 0; ct < 8; ++ct) {
      const int e = col0 + ct * 16 + lidx;
      bv[ct] = bias[2 * E_DIM + e]; pv[ct] = pw[e]; sv[ct] = sw[e];
    }
#pragma unroll
    for (int rt = 0; rt < 2; ++rt)
#pragma unroll
      for (int ct = 0; ct < 8; ++ct) {
        const int e = col0 + ct * 16 + lidx;
        const int h = e >> 6, d = e & 63;
#pragma unroll
        for (int reg = 0; reg < 4; ++reg) {
          const int R = row0 + wv * 32 + rt * 16 + quad * 4 + reg;
          const int lpos = R >> 2, nb = R & 3;
          const float y = acc[rt][ct][reg] + bv[ct];
          const float vp = fmaxf(y + sv[ct], EPS_F);
          ubuf[(((size_t)nb * N_HEADS + h) * L_SEQ + lpos) * H_DIM + d] =
              __powf(vp, pv[ct]);
        }
      }
  }
}

// ---------------------------------------------------------------------------
// Kernel T: transpose u (n,h,l,d) fp32 -> u^T (n,h,d,l) fp16.
// ---------------------------------------------------------------------------
__global__ __launch_bounds__(256) void transp_kernel(
    const float* __restrict__ u, _Float16* __restrict__ uT) {
  __shared__ float T[64][65];
  const int lt = blockIdx.x, h = blockIdx.y, nb = blockIdx.z;
  const int tid = threadIdx.x;
  const int r = tid >> 2;
  const int cb = (tid & 3) * 16;
  const size_t srcbase = ((size_t)nb * N_HEADS + h) * L_SEQ + lt * 64;
  {
    const float* p = u + (srcbase + r) * H_DIM + cb;
    *(float4*)&T[r][cb + 0]  = ((const float4*)p)[0];
    *(float4*)&T[r][cb + 4]  = ((const float4*)p)[1];
    *(float4*)&T[r][cb + 8]  = ((const float4*)p)[2];
    *(float4*)&T[r][cb + 12] = ((const float4*)p)[3];
  }
  __syncthreads();
  alignas(16) _Float16 hv[16];
#pragma unroll
  for (int j = 0; j < 16; ++j) hv[j] = (_Float16)T[cb + j][r];
  const size_t dst = (((size_t)nb * N_HEADS + h) * H_DIM + r) * L_SEQ + lt * 64 + cb;
  *(uint4*)(uT + dst)     = ((const uint4*)hv)[0];
  *(uint4*)(uT + dst + 8) = ((const uint4*)hv)[1];
}

// ---------------------------------------------------------------------------
// Kernel B: fp16 MFMA flash attention, S^T orientation (A=K, B=Q).
//
// v2 (occupancy rework): old version ran 512 blocks x 2 waves = exactly
// 1 wave/SIMD -> latency-bound (MfmaUtil 11.5%, Occupancy 9.7%).  Softmax is
// fixed-max exp2, so partial (o, l) over disjoint s-ranges combine linearly:
// split the s-loop 4 ways ACROSS WAVES of a 512-thread block.
//   8 waves = 4 s-groups (sg) x 2 q-halves (wv).  Per iteration the block
//   stages 256 s-rows (Ks[256][72] f16, Us[64][280] f16 = 71 KB); wave sg
//   consumes rows [sg*64, sg*64+64).  Loop count 32 -> 8.
//   Us row stride 280 (not 264/272): staging-write chunk starts
//   (12*r+16*j)%32 hit every bank pair exactly twice -> 8 lanes/bank
//   = the wave64 x 16B minimum (conflict-free); frag reads likewise.
// Cross-sg tree-reduce of o/lsum in LDS (union over the staging buffer,
// XOR-swizzled columns -> conflict-free), then the sg==0 waves run the GeM
// epilogue.  2 blocks/CU x 8 waves = 16 waves/CU = 4 waves/SIMD (VGPR 128).
// Grid 512 blocks x 512 thr.
// ---------------------------------------------------------------------------
__global__ __launch_bounds__(512, 4) void attn_kernel(
    const _Float16* __restrict__ qbuf, const _Float16* __restrict__ kbuf,
    const _Float16* __restrict__ uT, const float* __restrict__ pw,
    const float* __restrict__ sw, __hip_bfloat16* __restrict__ ohhi,
    __hip_bfloat16* __restrict__ ohlo) {
  __shared__ union {
    struct { _Float16 Ks[256][72]; _Float16 Us[64][280]; } st;
    struct { float A[2][64][64]; float B[2][64][64];
             float lA[2][2][64]; float lB[2][2][64]; } red;
  } sm;
  const int qt = blockIdx.x, h = blockIdx.y, nb = blockIdx.z;
  const int q0 = qt * 128;
  const int tid = threadIdx.x;
  const int lane = tid & 63;
  const int w = tid >> 6;           // wave 0..7
  const int wv = w & 1;             // q-half of the block tile
  const int sg = w >> 1;            // s-group 0..3
  const int lm = lane & 31;
  const int kg = lane >> 5;         // k-group within MFMA operands
  const int srow = tid >> 1;        // K staging row 0..255
  const int scb = (tid & 1) * 32;   // K staging col base (fp16 units)
  const int urow = tid >> 3;        // U staging row (d) 0..63
  const int ucb = (tid & 7) * 32;   // U staging col base (s units)
  const size_t headbase = ((size_t)nb * N_HEADS + h) * L_SEQ;
  const size_t dbase = ((size_t)nb * N_HEADS + h) * H_DIM;

  // hoist Q B-frags straight from global (no Q LDS): q(nt) = q0+wv*64+nt*32+lm
  f16x8 bq[2][4];
#pragma unroll
  for (int nt = 0; nt < 2; ++nt)
#pragma unroll
    for (int kc = 0; kc < 4; ++kc)
      bq[nt][kc] = *(const f16x8*)(qbuf +
          (headbase + q0 + wv * 64 + nt * 32 + lm) * H_DIM + kc * 16 + kg * 8);

  f32x16 o[2][2];  // [q-half nt][d-half mt2]
  o[0][0] = (f32x16)(0.f); o[0][1] = (f32x16)(0.f);
  o[1][0] = (f32x16)(0.f); o[1][1] = (f32x16)(0.f);
  float lsum[2] = {0.f, 0.f};

  for (int it = 0; it < 8; ++it) {
    const int s0 = it * 256;
    __syncthreads();  // prior iteration's frag reads complete
    {
      const _Float16* kp = kbuf + (headbase + s0 + srow) * H_DIM + scb;
      *(uint4*)&sm.st.Ks[srow][scb + 0]  = ((const uint4*)kp)[0];
      *(uint4*)&sm.st.Ks[srow][scb + 8]  = ((const uint4*)kp)[1];
      *(uint4*)&sm.st.Ks[srow][scb + 16] = ((const uint4*)kp)[2];
      *(uint4*)&sm.st.Ks[srow][scb + 24] = ((const uint4*)kp)[3];
      const _Float16* up = uT + (dbase + urow) * L_SEQ + s0 + ucb;
      *(uint4*)&sm.st.Us[urow][ucb + 0]  = ((const uint4*)up)[0];
      *(uint4*)&sm.st.Us[urow][ucb + 8]  = ((const uint4*)up)[1];
      *(uint4*)&sm.st.Us[urow][ucb + 16] = ((const uint4*)up)[2];
      *(uint4*)&sm.st.Us[urow][ucb + 24] = ((const uint4*)up)[3];
    }
    __syncthreads();

    const int sr = sg * 64;  // this wave's s-rows within the staged 256

    // ---- S^T: sc[nt][mt], C-layout row = s_local, col = q (lane&31) ----
    f32x16 sc[2][2];
    sc[0][0] = (f32x16)(0.f); sc[0][1] = (f32x16)(0.f);
    sc[1][0] = (f32x16)(0.f); sc[1][1] = (f32x16)(0.f);
#pragma unroll
    for (int kc = 0; kc < 4; ++kc) {
      const f16x8 ak0 = *(const f16x8*)&sm.st.Ks[sr + lm][kc * 16 + kg * 8];
      const f16x8 ak1 = *(const f16x8*)&sm.st.Ks[sr + 32 + lm][kc * 16 + kg * 8];
      sc[0][0] = __builtin_amdgcn_mfma_f32_32x32x16_f16(ak0, bq[0][kc], sc[0][0], 0, 0, 0);
      sc[0][1] = __builtin_amdgcn_mfma_f32_32x32x16_f16(ak1, bq[0][kc], sc[0][1], 0, 0, 0);
      sc[1][0] = __builtin_amdgcn_mfma_f32_32x32x16_f16(ak0, bq[1][kc], sc[1][0], 0, 0, 0);
      sc[1][1] = __builtin_amdgcn_mfma_f32_32x32x16_f16(ak1, bq[1][kc], sc[1][1], 0, 0, 0);
    }

    // ---- p = exp2(score); pack fp16 pairs; per-lane l partial sum ----
    unsigned int P2[2][2][4][2];
#pragma unroll
    for (int nt = 0; nt < 2; ++nt)
#pragma unroll
      for (int mt = 0; mt < 2; ++mt)
#pragma unroll
        for (int g = 0; g < 4; ++g) {
          const float p0 = __builtin_amdgcn_exp2f(sc[nt][mt][4 * g + 0]);
          const float p1 = __builtin_amdgcn_exp2f(sc[nt][mt][4 * g + 1]);
          const float p2 = __builtin_amdgcn_exp2f(sc[nt][mt][4 * g + 2]);
          const float p3 = __builtin_amdgcn_exp2f(sc[nt][mt][4 * g + 3]);
          lsum[nt] += (p0 + p1) + (p2 + p3);
          P2[nt][mt][g][0] = packf16(p0, p1);
          P2[nt][mt][g][1] = packf16(p2, p3);
        }

    // ---- PV: O^T += U^T @ P^T; P B-frags via xor-32 exchange ----
#pragma unroll
    for (int kc = 0; kc < 4; ++kc) {
      const int mt = kc >> 1;
      const f16x8 au0 = *(const f16x8*)&sm.st.Us[lm][sr + kc * 16 + kg * 8];
      const f16x8 au1 = *(const f16x8*)&sm.st.Us[32 + lm][sr + kc * 16 + kg * 8];
#pragma unroll
      for (int nt = 0; nt < 2; ++nt) {
        const int gx = (2 * kc) & 3, gy = (2 * kc + 1) & 3;
        const unsigned int x0 = P2[nt][mt][gx][0], x1 = P2[nt][mt][gx][1];
        const unsigned int y0 = P2[nt][mt][gy][0], y1 = P2[nt][mt][gy][1];
        const unsigned int sA = kg ? x0 : y0, sB = kg ? x1 : y1;
        const unsigned int rA = (unsigned int)__shfl_xor((int)sA, 32);
        const unsigned int rB = (unsigned int)__shfl_xor((int)sB, 32);
        union { unsigned int u[4]; f16x8 v; } bp;
        bp.u[0] = kg ? rA : x0;  // j0..3: s = kc*16+kg*8+0..3
        bp.u[1] = kg ? rB : x1;
        bp.u[2] = kg ? y0 : rA;  // j4..7: s = kc*16+kg*8+4..7
        bp.u[3] = kg ? y1 : rB;
        o[nt][0] = __builtin_amdgcn_mfma_f32_32x32x16_f16(au0, bp.v, o[nt][0], 0, 0, 0);
        o[nt][1] = __builtin_amdgcn_mfma_f32_32x32x16_f16(au1, bp.v, o[nt][1], 0, 0, 0);
      }
    }
  }

  // ---- cross-s-group tree reduction in LDS (sg1->A, sg3->B; sg0+=A,
  //      sg2+=B then republishes B; sg0+=B).  XOR-swizzled columns keep
  //      float4 accesses at 8 lanes/bank (conflict-free).  ----
  float* redA = &sm.red.A[0][0][0];
  float* redB = &sm.red.B[0][0][0];
  float* lrA = &sm.red.lA[0][0][0];
  float* lrB = &sm.red.lB[0][0][0];

  auto publish = [&](float* dst, float* ldst) {
#pragma unroll
    for (int nt = 0; nt < 2; ++nt) {
      ldst[(wv * 2 + nt) * 64 + lane] = lsum[nt];
#pragma unroll
      for (int mt2 = 0; mt2 < 2; ++mt2)
#pragma unroll
        for (int g = 0; g < 4; ++g) {
          const int i4 = ((nt * 2 + mt2) * 4 + g) ^ (lane & 7);
          float4 v = {o[nt][mt2][4 * g + 0], o[nt][mt2][4 * g + 1],
                      o[nt][mt2][4 * g + 2], o[nt][mt2][4 * g + 3]};
          *(float4*)(dst + ((size_t)(wv * 64 + lane)) * 64 + i4 * 4) = v;
        }
    }
  };
  auto accum = [&](const float* srcp, const float* lsrc) {
#pragma unroll
    for (int nt = 0; nt < 2; ++nt) {
      lsum[nt] += lsrc[(wv * 2 + nt) * 64 + lane];
#pragma unroll
      for (int mt2 = 0; mt2 < 2; ++mt2)
#pragma unroll
        for (int g = 0; g < 4; ++g) {
          const int i4 = ((nt * 2 + mt2) * 4 + g) ^ (lane & 7);
          const float4 v =
              *(const float4*)(srcp + ((size_t)(wv * 64 + lane)) * 64 + i4 * 4);
          o[nt][mt2][4 * g + 0] += v.x; o[nt][mt2][4 * g + 1] += v.y;
          o[nt][mt2][4 * g + 2] += v.z; o[nt][mt2][4 * g + 3] += v.w;
        }
    }
  };

  __syncthreads();  // loop's trailing frag reads complete before LDS reuse
  if (sg == 1) publish(redA, lrA);
  if (sg == 3) publish(redB, lrB);
  __syncthreads();
  if (sg == 0) accum(redA, lrA);
  if (sg == 2) {
    accum(redB, lrB);     // same-wave read-then-write: ordered
    publish(redB, lrB);   // republish the sg2+sg3 sum
  }
  __syncthreads();
  if (sg != 0) return;    // no barriers past this point
  accum(redB, lrB);

  // ---- epilogue: finish l across kg halves, GeM inverse, packed stores ----
#pragma unroll
  for (int nt = 0; nt < 2; ++nt) {
    const float l = lsum[nt] + __shfl_xor(lsum[nt], 32);
    const float inv = 1.0f / l;
    const int qg = q0 + wv * 64 + nt * 32 + lm;
    const size_t base = ((size_t)qg * N_BATCH + nb) * E_DIM + h * H_DIM;
#pragma unroll
    for (int mt2 = 0; mt2 < 2; ++mt2)
#pragma unroll
      for (int g = 0; g < 4; ++g) {
        alignas(8) __hip_bfloat16 hb[4], lb[4];
#pragma unroll
        for (int i = 0; i < 4; ++i) {
          const int d = mt2 * 32 + 8 * g + 4 * kg + i;
          const int e = h * H_DIM + d;
          const float pooled = o[nt][mt2][4 * g + i] * inv;
          const float val = __powf(fmaxf(pooled, EPS_F), 1.0f / pw[e]) - sw[e];
          split2(val, hb[i], lb[i]);
        }
        const int d0 = mt2 * 32 + 8 * g + 4 * kg;
        *(uint2*)(ohhi + base + d0) = *(const uint2*)hb;
        *(uint2*)(ohlo + base + d0) = *(const uint2*)lb;
      }
  }
}

// ---------------------------------------------------------------------------
// Kernel C: output projection via MFMA, hi/lo 3-pass.  (unchanged)
// ---------------------------------------------------------------------------
__global__ __launch_bounds__(256, 4) void out_proj_kernel(
    const __hip_bfloat16* __restrict__ xhi, const __hip_bfloat16* __restrict__ xlo,
    const __hip_bfloat16* __restrict__ whi, const __hip_bfloat16* __restrict__ wlo,
    const float* __restrict__ bias, float* __restrict__ out) {
  __shared__ __hip_bfloat16 Xh[128][40];
  __shared__ __hip_bfloat16 Xl[128][40];
  __shared__ __hip_bfloat16 Wh[64][40];
  __shared__ __hip_bfloat16 Wl[64][40];
  const int row0 = blockIdx.x * 128;
  const int col0 = blockIdx.y * 64;
  const int tid = threadIdx.x;
  const int lane = tid & 63;
  const int wv = tid >> 6;
  const int lidx = lane & 15;
  const int quad = lane >> 4;
  const int srow = tid >> 1;
  const int scol = (tid & 1) * 16;
  const int wrow = tid >> 2;
  const int wcol = (tid & 3) * 8;

  f32x4 acc[2][4];
#pragma unroll
  for (int rt = 0; rt < 2; ++rt)
#pragma unroll
    for (int ct = 0; ct < 4; ++ct) acc[rt][ct] = (f32x4){0.f, 0.f, 0.f, 0.f};

  const int ar0 = wv * 32 + lidx;

  for (int kt = 0; kt < 16; ++kt) {
    const int k0 = kt * 32;
    {
      const size_t xof = (size_t)(row0 + srow) * E_DIM + k0 + scol;
      *(uint4*)&Xh[srow][scol]     = ((const uint4*)(xhi + xof))[0];
      *(uint4*)&Xh[srow][scol + 8] = ((const uint4*)(xhi + xof))[1];
      *(uint4*)&Xl[srow][scol]     = ((const uint4*)(xlo + xof))[0];
      *(uint4*)&Xl[srow][scol + 8] = ((const uint4*)(xlo + xof))[1];
      const size_t wof = (size_t)(col0 + wrow) * E_DIM + k0 + wcol;
      *(uint4*)&Wh[wrow][wcol] = *(const uint4*)(whi + wof);
      *(uint4*)&Wl[wrow][wcol] = *(const uint4*)(wlo + wof);
    }
    __syncthreads();

    const bf16x8 ah0 = *(const bf16x8*)&Xh[ar0][quad * 8];
    const bf16x8 ah1 = *(const bf16x8*)&Xh[ar0 + 16][quad * 8];
    const bf16x8 al0 = *(const bf16x8*)&Xl[ar0][quad * 8];
    const bf16x8 al1 = *(const bf16x8*)&Xl[ar0 + 16][quad * 8];
#pragma unroll
    for (int ct = 0; ct < 4; ++ct) {
      const bf16x8 bh = *(const bf16x8*)&Wh[ct * 16 + lidx][quad * 8];
      const bf16x8 bl = *(const bf16x8*)&Wl[ct * 16 + lidx][quad * 8];
      acc[0][ct] = __builtin_amdgcn_mfma_f32_16x16x32_bf16(ah0, bh, acc[0][ct], 0, 0, 0);
      acc[0][ct] = __builtin_amdgcn_mfma_f32_16x16x32_bf16(al0, bh, acc[0][ct], 0, 0, 0);
      acc[0][ct] = __builtin_amdgcn_mfma_f32_16x16x32_bf16(ah0, bl, acc[0][ct], 0, 0, 0);
      acc[1][ct] = __builtin_amdgcn_mfma_f32_16x16x32_bf16(ah1, bh, acc[1][ct], 0, 0, 0);
      acc[1][ct] = __builtin_amdgcn_mfma_f32_16x16x32_bf16(al1, bh, acc[1][ct], 0, 0, 0);
      acc[1][ct] = __builtin_amdgcn_mfma_f32_16x16x32_bf16(ah1, bl, acc[1][ct], 0, 0, 0);
    }
    __syncthreads();
  }

  float bv[4];
#pragma unroll
  for (int ct = 0; ct < 4; ++ct) bv[ct] = bias[col0 + ct * 16 + lidx];
#pragma unroll
  for (int rt = 0; rt < 2; ++rt)
#pragma unroll
    for (int ct = 0; ct < 4; ++ct) {
      const int c = col0 + ct * 16 + lidx;
#pragma unroll
      for (int reg = 0; reg < 4; ++reg) {
        const int R = row0 + wv * 32 + rt * 16 + quad * 4 + reg;
        out[(size_t)R * E_DIM + c] = acc[rt][ct][reg] + bv[ct];
      }
    }
}

extern "C" void kernel_launch(void* const* d_in, const int* in_sizes, int n_in,
                              void* d_out, int out_size, void* d_ws, size_t ws_size,
                              hipStream_t stream) {
  const float* q_in = (const float*)d_in[0];
  const float* k_in = (const float*)d_in[1];
  const float* v_in = (const float*)d_in[2];
  const float* wio  = (const float*)d_in[3];
  const float* bio  = (const float*)d_in[4];
  const float* wo   = (const float*)d_in[5];
  const float* bo   = (const float*)d_in[6];
  const float* pw   = (const float*)d_in[7];
  const float* sw   = (const float*)d_in[8];

  // Workspace: qbuf,kbuf f16 (8 MiB ea); ubuf fp32 16 MiB (reused as
  // ohhi/ohlo bf16 8+8 after transp); uT f16 8 MiB; weight splits ~4 MiB.
  const size_t NE = (size_t)N_ROWS * E_DIM;
  _Float16* qbuf = (_Float16*)d_ws;
  _Float16* kbuf = qbuf + NE;
  float* ubuf = (float*)(kbuf + NE);
  _Float16* uT = (_Float16*)(ubuf + NE);
  __hip_bfloat16* wiohi = (__hip_bfloat16*)(uT + NE);
  __hip_bfloat16* wiolo = wiohi + 786432;
  __hip_bfloat16* wohi  = wiolo + 786432;
  __hip_bfloat16* wolo  = wohi + 262144;
  __hip_bfloat16* ohhi = (__hip_bfloat16*)ubuf;  // alias: ubuf dead after transp
  __hip_bfloat16* ohlo = ohhi + NE;

  wconv_kernel<<<dim3(1024), 256, 0, stream>>>(wio, wo, wiohi, wiolo, wohi, wolo);
  proj_qkv_kernel<<<dim3(64, 4, 3), 256, 0, stream>>>(q_in, k_in, v_in, wiohi,
                                                      bio, pw, sw, qbuf, kbuf, ubuf);
  transp_kernel<<<dim3(32, 8, 4), 256, 0, stream>>>(ubuf, uT);
  attn_kernel<<<dim3(16, 8, 4), 512, 0, stream>>>(qbuf, kbuf, uT, pw, sw,
                                                  ohhi, ohlo);
  out_proj_kernel<<<dim3(64, 8), 256, 0, stream>>>(ohhi, ohlo, wohi, wolo,
                                                   bo, (float*)d_out);
}

// Round 2
// 283.147 us; speedup vs baseline: 1.5880x; 1.5880x over previous
//
#include <hip/hip_runtime.h>
#include <hip/hip_bf16.h>

// Problem constants (L,N,E,H,D) = (2048,4,512,8,64)
#define E_DIM 512
#define N_BATCH 4
#define L_SEQ 2048
#define N_HEADS 8
#define H_DIM 64
#define N_ROWS (L_SEQ * N_BATCH) /* 8192 */
#define EPS_F 1e-6f
#define SC_Q 0.18033688f  /* 0.125 * log2(e): scores come out in log2 space */

typedef __attribute__((ext_vector_type(8))) short bf16x8;
typedef __attribute__((ext_vector_type(8))) _Float16 f16x8;
typedef __attribute__((ext_vector_type(4))) float f32x4;
typedef __attribute__((ext_vector_type(16))) float f32x16;

__device__ __forceinline__ void split2(float f, __hip_bfloat16& h, __hip_bfloat16& l) {
  h = __float2bfloat16(f);
  l = __float2bfloat16(f - __bfloat162float(h));
}

__device__ __forceinline__ unsigned int packf16(float a, float b) {
  union { _Float16 h[2]; unsigned int u; } c;
  c.h[0] = (_Float16)a;  // RN casts: unbiased (RTZ pkrtz would bias softmax weights)
  c.h[1] = (_Float16)b;
  return c.u;
}

// ---------------------------------------------------------------------------
// Kernel W: pre-split weights fp32 -> bf16 hi/lo.  (wiolo now unused by proj
// but kept for layout stability; wohi/wolo feed out_proj.)
// ---------------------------------------------------------------------------
__global__ __launch_bounds__(256) void wconv_kernel(
    const float* __restrict__ wio, const float* __restrict__ wo,
    __hip_bfloat16* __restrict__ wiohi, __hip_bfloat16* __restrict__ wiolo,
    __hip_bfloat16* __restrict__ wohi, __hip_bfloat16* __restrict__ wolo) {
  const int g = blockIdx.x * 256 + threadIdx.x;
  const float* src;
  __hip_bfloat16 *dh, *dl;
  int i;
  if (g < 196608) { src = wio; dh = wiohi; dl = wiolo; i = g * 4; }
  else            { src = wo;  dh = wohi;  dl = wolo;  i = (g - 196608) * 4; }
  const float4 f = *(const float4*)(src + i);
  alignas(8) __hip_bfloat16 h[4], l[4];
  split2(f.x, h[0], l[0]); split2(f.y, h[1], l[1]);
  split2(f.z, h[2], l[2]); split2(f.w, h[3], l[3]);
  *(uint2*)(dh + i) = *(const uint2*)h;
  *(uint2*)(dl + i) = *(const uint2*)l;
}

// ---------------------------------------------------------------------------
// Kernel A: packed QKV projection via MFMA, hi/lo 2-pass (hh + lh; the hl
// term x_hi*w_lo is dropped -- its ~6e-4 q/k/v error attenuates to ~2e-5
// through attention).  Q epilogue folds the 0.125*log2e softmax scale and
// stores fp16; K stores fp16; V stores u = max(v+sh,eps)^p fp32.
// ---------------------------------------------------------------------------
__global__ __launch_bounds__(256, 3) void proj_qkv_kernel(
    const float* __restrict__ xq, const float* __restrict__ xk,
    const float* __restrict__ xv, const __hip_bfloat16* __restrict__ whi,
    const float* __restrict__ bias, const float* __restrict__ pw,
    const float* __restrict__ sw,
    _Float16* __restrict__ qbuf, _Float16* __restrict__ kbuf,
    float* __restrict__ ubuf) {
  __shared__ __hip_bfloat16 Xh[128][40];
  __shared__ __hip_bfloat16 Xl[128][40];
  __shared__ __hip_bfloat16 Wh[128][40];
  const int z = blockIdx.z;
  const int row0 = blockIdx.x * 128;
  const int col0 = blockIdx.y * 128;
  const float* __restrict__ xsrc = (z == 0) ? xq : (z == 1) ? xk : xv;
  const int tid = threadIdx.x;
  const int lane = tid & 63;
  const int wv = tid >> 6;
  const int lidx = lane & 15;
  const int quad = lane >> 4;
  const int srow = tid >> 1;
  const int scol = (tid & 1) * 16;

  f32x4 acc[2][8];
#pragma unroll
  for (int rt = 0; rt < 2; ++rt)
#pragma unroll
    for (int ct = 0; ct < 8; ++ct) acc[rt][ct] = (f32x4){0.f, 0.f, 0.f, 0.f};

  const int ar0 = wv * 32 + lidx;

  for (int kt = 0; kt < 16; ++kt) {
    const int k0 = kt * 32;
    {
      const float* xp = xsrc + (size_t)(row0 + srow) * E_DIM + k0 + scol;
      float f[16];
      *(float4*)&f[0]  = ((const float4*)xp)[0];
      *(float4*)&f[4]  = ((const float4*)xp)[1];
      *(float4*)&f[8]  = ((const float4*)xp)[2];
      *(float4*)&f[12] = ((const float4*)xp)[3];
      alignas(16) __hip_bfloat16 hi[16], lo[16];
#pragma unroll
      for (int j = 0; j < 16; ++j) split2(f[j], hi[j], lo[j]);
      *(uint4*)&Xh[srow][scol]     = ((const uint4*)hi)[0];
      *(uint4*)&Xh[srow][scol + 8] = ((const uint4*)hi)[1];
      *(uint4*)&Xl[srow][scol]     = ((const uint4*)lo)[0];
      *(uint4*)&Xl[srow][scol + 8] = ((const uint4*)lo)[1];
    }
    {
      const size_t wof = (size_t)(z * E_DIM + col0 + srow) * E_DIM + k0 + scol;
      *(uint4*)&Wh[srow][scol]     = ((const uint4*)(whi + wof))[0];
      *(uint4*)&Wh[srow][scol + 8] = ((const uint4*)(whi + wof))[1];
    }
    __syncthreads();

    const bf16x8 ah0 = *(const bf16x8*)&Xh[ar0][quad * 8];
    const bf16x8 ah1 = *(const bf16x8*)&Xh[ar0 + 16][quad * 8];
    const bf16x8 al0 = *(const bf16x8*)&Xl[ar0][quad * 8];
    const bf16x8 al1 = *(const bf16x8*)&Xl[ar0 + 16][quad * 8];
#pragma unroll
    for (int ct = 0; ct < 8; ++ct) {
      const bf16x8 bh = *(const bf16x8*)&Wh[ct * 16 + lidx][quad * 8];
      acc[0][ct] = __builtin_amdgcn_mfma_f32_16x16x32_bf16(ah0, bh, acc[0][ct], 0, 0, 0);
      acc[0][ct] = __builtin_amdgcn_mfma_f32_16x16x32_bf16(al0, bh, acc[0][ct], 0, 0, 0);
      acc[1][ct] = __builtin_amdgcn_mfma_f32_16x16x32_bf16(ah1, bh, acc[1][ct], 0, 0, 0);
      acc[1][ct] = __builtin_amdgcn_mfma_f32_16x16x32_bf16(al1, bh, acc[1][ct], 0, 0, 0);
    }
    __syncthreads();
  }

  if (z < 2) {
    _Float16* __restrict__ dst = (z == 0) ? qbuf : kbuf;
    const float scale = (z == 0) ? SC_Q : 1.0f;
    float bv[8];
#pragma unroll
    for (int ct = 0; ct < 8; ++ct) bv[ct] = bias[z * E_DIM + col0 + ct * 16 + lidx];
#pragma unroll
    for (int rt = 0; rt < 2; ++rt)
#pragma unroll
      for (int ct = 0; ct < 8; ++ct) {
        const int e = col0 + ct * 16 + lidx;
        const int h = e >> 6, d = e & 63;
#pragma unroll
        for (int reg = 0; reg < 4; ++reg) {
          const int R = row0 + wv * 32 + rt * 16 + quad * 4 + reg;
          const int lpos = R >> 2, nb = R & 3;
          dst[(((size_t)nb * N_HEADS + h) * L_SEQ + lpos) * H_DIM + d] =
              (_Float16)((acc[rt][ct][reg] + bv[ct]) * scale);
        }
      }
  } else {
    float bv[8], pv[8], sv[8];
#pragma unroll
    for (int ct = 0; ct < 8; ++ct) {
      const int e = col0 + ct * 16 + lidx;
      bv[ct] = bias[2 * E_DIM + e]; pv[ct] = pw[e]; sv[ct] = sw[e];
    }
#pragma unroll
    for (int rt = 0; rt < 2; ++rt)
#pragma unroll
      for (int ct = 0; ct < 8; ++ct) {
        const int e = col0 + ct * 16 + lidx;
        const int h = e >> 6, d = e & 63;
#pragma unroll
        for (int reg = 0; reg < 4; ++reg) {
          const int R = row0 + wv * 32 + rt * 16 + quad * 4 + reg;
          const int lpos = R >> 2, nb = R & 3;
          const float y = acc[rt][ct][reg] + bv[ct];
          const float vp = fmaxf(y + sv[ct], EPS_F);
          ubuf[(((size_t)nb * N_HEADS + h) * L_SEQ + lpos) * H_DIM + d] =
              __powf(vp, pv[ct]);
        }
      }
  }
}

// ---------------------------------------------------------------------------
// Kernel T: transpose u (n,h,l,d) fp32 -> u^T (n,h,d,l) fp16.
// ---------------------------------------------------------------------------
__global__ __launch_bounds__(256) void transp_kernel(
    const float* __restrict__ u, _Float16* __restrict__ uT) {
  __shared__ float T[64][65];
  const int lt = blockIdx.x, h = blockIdx.y, nb = blockIdx.z;
  const int tid = threadIdx.x;
  const int r = tid >> 2;
  const int cb = (tid & 3) * 16;
  const size_t srcbase = ((size_t)nb * N_HEADS + h) * L_SEQ + lt * 64;
  {
    const float* p = u + (srcbase + r) * H_DIM + cb;
    *(float4*)&T[r][cb + 0]  = ((const float4*)p)[0];
    *(float4*)&T[r][cb + 4]  = ((const float4*)p)[1];
    *(float4*)&T[r][cb + 8]  = ((const float4*)p)[2];
    *(float4*)&T[r][cb + 12] = ((const float4*)p)[3];
  }
  __syncthreads();
  alignas(16) _Float16 hv[16];
#pragma unroll
  for (int j = 0; j < 16; ++j) hv[j] = (_Float16)T[cb + j][r];
  const size_t dst = (((size_t)nb * N_HEADS + h) * H_DIM + r) * L_SEQ + lt * 64 + cb;
  *(uint4*)(uT + dst)     = ((const uint4*)hv)[0];
  *(uint4*)(uT + dst + 8) = ((const uint4*)hv)[1];
}

// ---------------------------------------------------------------------------
// Kernel B: fp16 MFMA flash attention, S^T orientation (A=K, B=Q) so P lives
// in registers in B-operand layout (q = lane&31): one shfl_xor(32) exchange
// replaces the LDS P round-trip.  O^T = U^T @ P^T; l = per-lane scalar sum.
//
// v3 (occupancy, take 2): v1 ran 512 blocks x 2 waves = 1 wave/SIMD ->
// latency-bound (MfmaUtil 11.5%, Occ 9.7%).  v2's 4-way wave split with
// launch_bounds(512,4) capped VGPR at 64 vs ~160 live -> total spill
// (FETCH 70->516MB, 2.4x slower).  Per-wave state here is ~190 regs incl
// AGPR accumulators, so 2 waves/SIMD is the structural cap; v3 targets
// exactly that: 4 waves/block (2 s-groups x 2 q-halves), 256 thr,
// launch_bounds(256,2) -> VGPR cap 256 (v1 compiled to 128; no spill).
// Per-wave work/layout identical to v1 (nt=2 keeps 2:1 A-frag amortization);
// staging doubles to 128 s-rows/iter, loop 32 -> 16 iters.  Fixed-max
// softmax => disjoint s-range (o,l) partials combine linearly: one LDS
// publish/accum step (XOR-swizzled float4 slots -> 8 dwords/bank minimum)
// merges sg1 into sg0, then sg0's two waves run the GeM epilogue.
// LDS: Ks[128][72] + Us[64][136] f16 = 35.8 KB (union'd with the 33.8 KB
// reduction buffer).  2 blocks/CU x 4 waves = 8 waves/CU = 2 waves/SIMD.
// Grid 512 blocks x 256 thr.
// ---------------------------------------------------------------------------
__global__ __launch_bounds__(256, 2) void attn_kernel(
    const _Float16* __restrict__ qbuf, const _Float16* __restrict__ kbuf,
    const _Float16* __restrict__ uT, const float* __restrict__ pw,
    const float* __restrict__ sw, __hip_bfloat16* __restrict__ ohhi,
    __hip_bfloat16* __restrict__ ohlo) {
  __shared__ union {
    struct { _Float16 Ks[128][72]; _Float16 Us[64][136]; } st;
    struct { float A[2][64][64]; float lA[2][2][64]; } red;
  } sm;
  const int qt = blockIdx.x, h = blockIdx.y, nb = blockIdx.z;
  const int q0 = qt * 128;
  const int tid = threadIdx.x;
  const int lane = tid & 63;
  const int w = tid >> 6;           // wave 0..3
  const int wv = w & 1;             // q-half of the block tile
  const int sg = w >> 1;            // s-group 0..1
  const int lm = lane & 31;
  const int kg = lane >> 5;         // k-group within MFMA operands
  const int srow = tid >> 1;        // K staging row 0..127
  const int scb = (tid & 1) * 32;   // K staging col base (fp16 units)
  const int urow = tid >> 2;        // U staging row (d) 0..63
  const int ucb = (tid & 3) * 32;   // U staging col base (s units)
  const size_t headbase = ((size_t)nb * N_HEADS + h) * L_SEQ;
  const size_t dbase = ((size_t)nb * N_HEADS + h) * H_DIM;

  // hoist Q B-frags straight from global (no Q LDS): q(nt) = q0+wv*64+nt*32+lm
  f16x8 bq[2][4];
#pragma unroll
  for (int nt = 0; nt < 2; ++nt)
#pragma unroll
    for (int kc = 0; kc < 4; ++kc)
      bq[nt][kc] = *(const f16x8*)(qbuf +
          (headbase + q0 + wv * 64 + nt * 32 + lm) * H_DIM + kc * 16 + kg * 8);

  f32x16 o[2][2];  // [q-half nt][d-half mt2]
  o[0][0] = (f32x16)(0.f); o[0][1] = (f32x16)(0.f);
  o[1][0] = (f32x16)(0.f); o[1][1] = (f32x16)(0.f);
  float lsum[2] = {0.f, 0.f};

  for (int it = 0; it < 16; ++it) {
    const int s0 = it * 128;
    __syncthreads();  // prior iteration's frag reads complete
    {
      const _Float16* kp = kbuf + (headbase + s0 + srow) * H_DIM + scb;
      *(uint4*)&sm.st.Ks[srow][scb + 0]  = ((const uint4*)kp)[0];
      *(uint4*)&sm.st.Ks[srow][scb + 8]  = ((const uint4*)kp)[1];
      *(uint4*)&sm.st.Ks[srow][scb + 16] = ((const uint4*)kp)[2];
      *(uint4*)&sm.st.Ks[srow][scb + 24] = ((const uint4*)kp)[3];
      const _Float16* up = uT + (dbase + urow) * L_SEQ + s0 + ucb;
      *(uint4*)&sm.st.Us[urow][ucb + 0]  = ((const uint4*)up)[0];
      *(uint4*)&sm.st.Us[urow][ucb + 8]  = ((const uint4*)up)[1];
      *(uint4*)&sm.st.Us[urow][ucb + 16] = ((const uint4*)up)[2];
      *(uint4*)&sm.st.Us[urow][ucb + 24] = ((const uint4*)up)[3];
    }
    __syncthreads();

    const int sr = sg * 64;  // this wave's s-rows within the staged 128

    // ---- S^T: sc[nt][mt], C-layout row = s_local, col = q (lane&31) ----
    f32x16 sc[2][2];
    sc[0][0] = (f32x16)(0.f); sc[0][1] = (f32x16)(0.f);
    sc[1][0] = (f32x16)(0.f); sc[1][1] = (f32x16)(0.f);
#pragma unroll
    for (int kc = 0; kc < 4; ++kc) {
      const f16x8 ak0 = *(const f16x8*)&sm.st.Ks[sr + lm][kc * 16 + kg * 8];
      const f16x8 ak1 = *(const f16x8*)&sm.st.Ks[sr + 32 + lm][kc * 16 + kg * 8];
      sc[0][0] = __builtin_amdgcn_mfma_f32_32x32x16_f16(ak0, bq[0][kc], sc[0][0], 0, 0, 0);
      sc[0][1] = __builtin_amdgcn_mfma_f32_32x32x16_f16(ak1, bq[0][kc], sc[0][1], 0, 0, 0);
      sc[1][0] = __builtin_amdgcn_mfma_f32_32x32x16_f16(ak0, bq[1][kc], sc[1][0], 0, 0, 0);
      sc[1][1] = __builtin_amdgcn_mfma_f32_32x32x16_f16(ak1, bq[1][kc], sc[1][1], 0, 0, 0);
    }

    // ---- p = exp2(score); pack fp16 pairs; per-lane l partial sum ----
    unsigned int P2[2][2][4][2];
#pragma unroll
    for (int nt = 0; nt < 2; ++nt)
#pragma unroll
      for (int mt = 0; mt < 2; ++mt)
#pragma unroll
        for (int g = 0; g < 4; ++g) {
          const float p0 = __builtin_amdgcn_exp2f(sc[nt][mt][4 * g + 0]);
          const float p1 = __builtin_amdgcn_exp2f(sc[nt][mt][4 * g + 1]);
          const float p2 = __builtin_amdgcn_exp2f(sc[nt][mt][4 * g + 2]);
          const float p3 = __builtin_amdgcn_exp2f(sc[nt][mt][4 * g + 3]);
          lsum[nt] += (p0 + p1) + (p2 + p3);
          P2[nt][mt][g][0] = packf16(p0, p1);
          P2[nt][mt][g][1] = packf16(p2, p3);
        }

    // ---- PV: O^T += U^T @ P^T; P B-frags via xor-32 exchange ----
#pragma unroll
    for (int kc = 0; kc < 4; ++kc) {
      const int mt = kc >> 1;
      const f16x8 au0 = *(const f16x8*)&sm.st.Us[lm][sr + kc * 16 + kg * 8];
      const f16x8 au1 = *(const f16x8*)&sm.st.Us[32 + lm][sr + kc * 16 + kg * 8];
#pragma unroll
      for (int nt = 0; nt < 2; ++nt) {
        const int gx = (2 * kc) & 3, gy = (2 * kc + 1) & 3;
        const unsigned int x0 = P2[nt][mt][gx][0], x1 = P2[nt][mt][gx][1];
        const unsigned int y0 = P2[nt][mt][gy][0], y1 = P2[nt][mt][gy][1];
        const unsigned int sA = kg ? x0 : y0, sB = kg ? x1 : y1;
        const unsigned int rA = (unsigned int)__shfl_xor((int)sA, 32);
        const unsigned int rB = (unsigned int)__shfl_xor((int)sB, 32);
        union { unsigned int u[4]; f16x8 v; } bp;
        bp.u[0] = kg ? rA : x0;  // j0..3: s = kc*16+kg*8+0..3
        bp.u[1] = kg ? rB : x1;
        bp.u[2] = kg ? y0 : rA;  // j4..7: s = kc*16+kg*8+4..7
        bp.u[3] = kg ? y1 : rB;
        o[nt][0] = __builtin_amdgcn_mfma_f32_32x32x16_f16(au0, bp.v, o[nt][0], 0, 0, 0);
        o[nt][1] = __builtin_amdgcn_mfma_f32_32x32x16_f16(au1, bp.v, o[nt][1], 0, 0, 0);
      }
    }
  }

  // ---- cross-s-group reduction in LDS: sg1 publishes (o, lsum), sg0
  //      accumulates.  XOR-swizzled float4 slots keep accesses at the
  //      8-dwords/bank wave64 minimum (conflict-free).  ----
  float* redA = &sm.red.A[0][0][0];
  float* lrA = &sm.red.lA[0][0][0];

  __syncthreads();  // loop's trailing frag reads complete before LDS reuse
  if (sg == 1) {
#pragma unroll
    for (int nt = 0; nt < 2; ++nt) {
      lrA[(wv * 2 + nt) * 64 + lane] = lsum[nt];
#pragma unroll
      for (int mt2 = 0; mt2 < 2; ++mt2)
#pragma unroll
        for (int g = 0; g < 4; ++g) {
          const int i4 = ((nt * 2 + mt2) * 4 + g) ^ (lane & 7);
          float4 v = {o[nt][mt2][4 * g + 0], o[nt][mt2][4 * g + 1],
                      o[nt][mt2][4 * g + 2], o[nt][mt2][4 * g + 3]};
          *(float4*)(redA + ((size_t)(wv * 64 + lane)) * 64 + i4 * 4) = v;
        }
    }
  }
  __syncthreads();
  if (sg == 1) return;  // sg0 past this point; no further barriers
#pragma unroll
  for (int nt = 0; nt < 2; ++nt) {
    lsum[nt] += lrA[(wv * 2 + nt) * 64 + lane];
#pragma unroll
    for (int mt2 = 0; mt2 < 2; ++mt2)
#pragma unroll
      for (int g = 0; g < 4; ++g) {
        const int i4 = ((nt * 2 + mt2) * 4 + g) ^ (lane & 7);
        const float4 v =
            *(const float4*)(redA + ((size_t)(wv * 64 + lane)) * 64 + i4 * 4);
        o[nt][mt2][4 * g + 0] += v.x; o[nt][mt2][4 * g + 1] += v.y;
        o[nt][mt2][4 * g + 2] += v.z; o[nt][mt2][4 * g + 3] += v.w;
      }
  }

  // ---- epilogue: finish l across kg halves, GeM inverse, packed stores ----
#pragma unroll
  for (int nt = 0; nt < 2; ++nt) {
    const float l = lsum[nt] + __shfl_xor(lsum[nt], 32);
    const float inv = 1.0f / l;
    const int qg = q0 + wv * 64 + nt * 32 + lm;
    const size_t base = ((size_t)qg * N_BATCH + nb) * E_DIM + h * H_DIM;
#pragma unroll
    for (int mt2 = 0; mt2 < 2; ++mt2)
#pragma unroll
      for (int g = 0; g < 4; ++g) {
        alignas(8) __hip_bfloat16 hb[4], lb[4];
#pragma unroll
        for (int i = 0; i < 4; ++i) {
          const int d = mt2 * 32 + 8 * g + 4 * kg + i;
          const int e = h * H_DIM + d;
          const float pooled = o[nt][mt2][4 * g + i] * inv;
          const float val = __powf(fmaxf(pooled, EPS_F), 1.0f / pw[e]) - sw[e];
          split2(val, hb[i], lb[i]);
        }
        const int d0 = mt2 * 32 + 8 * g + 4 * kg;
        *(uint2*)(ohhi + base + d0) = *(const uint2*)hb;
        *(uint2*)(ohlo + base + d0) = *(const uint2*)lb;
      }
  }
}

// ---------------------------------------------------------------------------
// Kernel C: output projection via MFMA, hi/lo 3-pass.  (unchanged)
// ---------------------------------------------------------------------------
__global__ __launch_bounds__(256, 4) void out_proj_kernel(
    const __hip_bfloat16* __restrict__ xhi, const __hip_bfloat16* __restrict__ xlo,
    const __hip_bfloat16* __restrict__ whi, const __hip_bfloat16* __restrict__ wlo,
    const float* __restrict__ bias, float* __restrict__ out) {
  __shared__ __hip_bfloat16 Xh[128][40];
  __shared__ __hip_bfloat16 Xl[128][40];
  __shared__ __hip_bfloat16 Wh[64][40];
  __shared__ __hip_bfloat16 Wl[64][40];
  const int row0 = blockIdx.x * 128;
  const int col0 = blockIdx.y * 64;
  const int tid = threadIdx.x;
  const int lane = tid & 63;
  const int wv = tid >> 6;
  const int lidx = lane & 15;
  const int quad = lane >> 4;
  const int srow = tid >> 1;
  const int scol = (tid & 1) * 16;
  const int wrow = tid >> 2;
  const int wcol = (tid & 3) * 8;

  f32x4 acc[2][4];
#pragma unroll
  for (int rt = 0; rt < 2; ++rt)
#pragma unroll
    for (int ct = 0; ct < 4; ++ct) acc[rt][ct] = (f32x4){0.f, 0.f, 0.f, 0.f};

  const int ar0 = wv * 32 + lidx;

  for (int kt = 0; kt < 16; ++kt) {
    const int k0 = kt * 32;
    {
      const size_t xof = (size_t)(row0 + srow) * E_DIM + k0 + scol;
      *(uint4*)&Xh[srow][scol]     = ((const uint4*)(xhi + xof))[0];
      *(uint4*)&Xh[srow][scol + 8] = ((const uint4*)(xhi + xof))[1];
      *(uint4*)&Xl[srow][scol]     = ((const uint4*)(xlo + xof))[0];
      *(uint4*)&Xl[srow][scol + 8] = ((const uint4*)(xlo + xof))[1];
      const size_t wof = (size_t)(col0 + wrow) * E_DIM + k0 + wcol;
      *(uint4*)&Wh[wrow][wcol] = *(const uint4*)(whi + wof);
      *(uint4*)&Wl[wrow][wcol] = *(const uint4*)(wlo + wof);
    }
    __syncthreads();

    const bf16x8 ah0 = *(const bf16x8*)&Xh[ar0][quad * 8];
    const bf16x8 ah1 = *(const bf16x8*)&Xh[ar0 + 16][quad * 8];
    const bf16x8 al0 = *(const bf16x8*)&Xl[ar0][quad * 8];
    const bf16x8 al1 = *(const bf16x8*)&Xl[ar0 + 16][quad * 8];
#pragma unroll
    for (int ct = 0; ct < 4; ++ct) {
      const bf16x8 bh = *(const bf16x8*)&Wh[ct * 16 + lidx][quad * 8];
      const bf16x8 bl = *(const bf16x8*)&Wl[ct * 16 + lidx][quad * 8];
      acc[0][ct] = __builtin_amdgcn_mfma_f32_16x16x32_bf16(ah0, bh, acc[0][ct], 0, 0, 0);
      acc[0][ct] = __builtin_amdgcn_mfma_f32_16x16x32_bf16(al0, bh, acc[0][ct], 0, 0, 0);
      acc[0][ct] = __builtin_amdgcn_mfma_f32_16x16x32_bf16(ah0, bl, acc[0][ct], 0, 0, 0);
      acc[1][ct] = __builtin_amdgcn_mfma_f32_16x16x32_bf16(ah1, bh, acc[1][ct], 0, 0, 0);
      acc[1][ct] = __builtin_amdgcn_mfma_f32_16x16x32_bf16(al1, bh, acc[1][ct], 0, 0, 0);
      acc[1][ct] = __builtin_amdgcn_mfma_f32_16x16x32_bf16(ah1, bl, acc[1][ct], 0, 0, 0);
    }
    __syncthreads();
  }

  float bv[4];
#pragma unroll
  for (int ct = 0; ct < 4; ++ct) bv[ct] = bias[col0 + ct * 16 + lidx];
#pragma unroll
  for (int rt = 0; rt < 2; ++rt)
#pragma unroll
    for (int ct = 0; ct < 4; ++ct) {
      const int c = col0 + ct * 16 + lidx;
#pragma unroll
      for (int reg = 0; reg < 4; ++reg) {
        const int R = row0 + wv * 32 + rt * 16 + quad * 4 + reg;
        out[(size_t)R * E_DIM + c] = acc[rt][ct][reg] + bv[ct];
      }
    }
}

extern "C" void kernel_launch(void* const* d_in, const int* in_sizes, int n_in,
                              void* d_out, int out_size, void* d_ws, size_t ws_size,
                              hipStream_t stream) {
  const float* q_in = (const float*)d_in[0];
  const float* k_in = (const float*)d_in[1];
  const float* v_in = (const float*)d_in[2];
  const float* wio  = (const float*)d_in[3];
  const float* bio  = (const float*)d_in[4];
  const float* wo   = (const float*)d_in[5];
  const float* bo   = (const float*)d_in[6];
  const float* pw   = (const float*)d_in[7];
  const float* sw   = (const float*)d_in[8];

  // Workspace: qbuf,kbuf f16 (8 MiB ea); ubuf fp32 16 MiB (reused as
  // ohhi/ohlo bf16 8+8 after transp); uT f16 8 MiB; weight splits ~4 MiB.
  const size_t NE = (size_t)N_ROWS * E_DIM;
  _Float16* qbuf = (_Float16*)d_ws;
  _Float16* kbuf = qbuf + NE;
  float* ubuf = (float*)(kbuf + NE);
  _Float16* uT = (_Float16*)(ubuf + NE);
  __hip_bfloat16* wiohi = (__hip_bfloat16*)(uT + NE);
  __hip_bfloat16* wiolo = wiohi + 786432;
  __hip_bfloat16* wohi  = wiolo + 786432;
  __hip_bfloat16* wolo  = wohi + 262144;
  __hip_bfloat16* ohhi = (__hip_bfloat16*)ubuf;  // alias: ubuf dead after transp
  __hip_bfloat16* ohlo = ohhi + NE;

  wconv_kernel<<<dim3(1024), 256, 0, stream>>>(wio, wo, wiohi, wiolo, wohi, wolo);
  proj_qkv_kernel<<<dim3(64, 4, 3), 256, 0, stream>>>(q_in, k_in, v_in, wiohi,
                                                      bio, pw, sw, qbuf, kbuf, ubuf);
  transp_kernel<<<dim3(32, 8, 4), 256, 0, stream>>>(ubuf, uT);
  attn_kernel<<<dim3(16, 8, 4), 256, 0, stream>>>(qbuf, kbuf, uT, pw, sw,
                                                  ohhi, ohlo);
  out_proj_kernel<<<dim3(64, 8), 256, 0, stream>>>(ohhi, ohlo, wohi, wolo,
                                                   bo, (float*)d_out);
}

// Round 6
// 272.938 us; speedup vs baseline: 1.6474x; 1.0374x over previous
//
#include <hip/hip_runtime.h>
#include <hip/hip_bf16.h>

// Problem constants (L,N,E,H,D) = (2048,4,512,8,64)
#define E_DIM 512
#define N_BATCH 4
#define L_SEQ 2048
#define N_HEADS 8
#define H_DIM 64
#define N_ROWS (L_SEQ * N_BATCH) /* 8192 */
#define EPS_F 1e-6f
#define SC_Q 0.18033688f  /* 0.125 * log2(e): scores come out in log2 space */

typedef __attribute__((ext_vector_type(8))) short bf16x8;
typedef __attribute__((ext_vector_type(8))) _Float16 f16x8;
typedef __attribute__((ext_vector_type(4))) float f32x4;
typedef __attribute__((ext_vector_type(16))) float f32x16;

__device__ __forceinline__ void split2(float f, __hip_bfloat16& h, __hip_bfloat16& l) {
  h = __float2bfloat16(f);
  l = __float2bfloat16(f - __bfloat162float(h));
}

__device__ __forceinline__ unsigned int packf16(float a, float b) {
  union { _Float16 h[2]; unsigned int u; } c;
  c.h[0] = (_Float16)a;  // RN casts: unbiased (RTZ pkrtz would bias softmax weights)
  c.h[1] = (_Float16)b;
  return c.u;
}

// ---------------------------------------------------------------------------
// Kernel W: pre-split weights fp32 -> bf16 hi/lo.  (wiolo now unused by proj
// but kept for layout stability; wohi/wolo feed out_proj.)
// ---------------------------------------------------------------------------
__global__ __launch_bounds__(256) void wconv_kernel(
    const float* __restrict__ wio, const float* __restrict__ wo,
    __hip_bfloat16* __restrict__ wiohi, __hip_bfloat16* __restrict__ wiolo,
    __hip_bfloat16* __restrict__ wohi, __hip_bfloat16* __restrict__ wolo) {
  const int g = blockIdx.x * 256 + threadIdx.x;
  const float* src;
  __hip_bfloat16 *dh, *dl;
  int i;
  if (g < 196608) { src = wio; dh = wiohi; dl = wiolo; i = g * 4; }
  else            { src = wo;  dh = wohi;  dl = wolo;  i = (g - 196608) * 4; }
  const float4 f = *(const float4*)(src + i);
  alignas(8) __hip_bfloat16 h[4], l[4];
  split2(f.x, h[0], l[0]); split2(f.y, h[1], l[1]);
  split2(f.z, h[2], l[2]); split2(f.w, h[3], l[3]);
  *(uint2*)(dh + i) = *(const uint2*)h;
  *(uint2*)(dl + i) = *(const uint2*)l;
}

// ---------------------------------------------------------------------------
// Kernel A: packed QKV projection via MFMA, hi/lo 2-pass (hh + lh; the hl
// term x_hi*w_lo is dropped -- its ~6e-4 q/k/v error attenuates to ~2e-5
// through attention).  Q epilogue folds the 0.125*log2e softmax scale and
// stores fp16; K stores fp16; V stores u = max(v+sh,eps)^p fp32.
// ---------------------------------------------------------------------------
__global__ __launch_bounds__(256, 3) void proj_qkv_kernel(
    const float* __restrict__ xq, const float* __restrict__ xk,
    const float* __restrict__ xv, const __hip_bfloat16* __restrict__ whi,
    const float* __restrict__ bias, const float* __restrict__ pw,
    const float* __restrict__ sw,
    _Float16* __restrict__ qbuf, _Float16* __restrict__ kbuf,
    float* __restrict__ ubuf) {
  __shared__ __hip_bfloat16 Xh[128][40];
  __shared__ __hip_bfloat16 Xl[128][40];
  __shared__ __hip_bfloat16 Wh[128][40];
  const int z = blockIdx.z;
  const int row0 = blockIdx.x * 128;
  const int col0 = blockIdx.y * 128;
  const float* __restrict__ xsrc = (z == 0) ? xq : (z == 1) ? xk : xv;
  const int tid = threadIdx.x;
  const int lane = tid & 63;
  const int wv = tid >> 6;
  const int lidx = lane & 15;
  const int quad = lane >> 4;
  const int srow = tid >> 1;
  const int scol = (tid & 1) * 16;

  f32x4 acc[2][8];
#pragma unroll
  for (int rt = 0; rt < 2; ++rt)
#pragma unroll
    for (int ct = 0; ct < 8; ++ct) acc[rt][ct] = (f32x4){0.f, 0.f, 0.f, 0.f};

  const int ar0 = wv * 32 + lidx;

  for (int kt = 0; kt < 16; ++kt) {
    const int k0 = kt * 32;
    {
      const float* xp = xsrc + (size_t)(row0 + srow) * E_DIM + k0 + scol;
      float f[16];
      *(float4*)&f[0]  = ((const float4*)xp)[0];
      *(float4*)&f[4]  = ((const float4*)xp)[1];
      *(float4*)&f[8]  = ((const float4*)xp)[2];
      *(float4*)&f[12] = ((const float4*)xp)[3];
      alignas(16) __hip_bfloat16 hi[16], lo[16];
#pragma unroll
      for (int j = 0; j < 16; ++j) split2(f[j], hi[j], lo[j]);
      *(uint4*)&Xh[srow][scol]     = ((const uint4*)hi)[0];
      *(uint4*)&Xh[srow][scol + 8] = ((const uint4*)hi)[1];
      *(uint4*)&Xl[srow][scol]     = ((const uint4*)lo)[0];
      *(uint4*)&Xl[srow][scol + 8] = ((const uint4*)lo)[1];
    }
    {
      const size_t wof = (size_t)(z * E_DIM + col0 + srow) * E_DIM + k0 + scol;
      *(uint4*)&Wh[srow][scol]     = ((const uint4*)(whi + wof))[0];
      *(uint4*)&Wh[srow][scol + 8] = ((const uint4*)(whi + wof))[1];
    }
    __syncthreads();

    const bf16x8 ah0 = *(const bf16x8*)&Xh[ar0][quad * 8];
    const bf16x8 ah1 = *(const bf16x8*)&Xh[ar0 + 16][quad * 8];
    const bf16x8 al0 = *(const bf16x8*)&Xl[ar0][quad * 8];
    const bf16x8 al1 = *(const bf16x8*)&Xl[ar0 + 16][quad * 8];
#pragma unroll
    for (int ct = 0; ct < 8; ++ct) {
      const bf16x8 bh = *(const bf16x8*)&Wh[ct * 16 + lidx][quad * 8];
      acc[0][ct] = __builtin_amdgcn_mfma_f32_16x16x32_bf16(ah0, bh, acc[0][ct], 0, 0, 0);
      acc[0][ct] = __builtin_amdgcn_mfma_f32_16x16x32_bf16(al0, bh, acc[0][ct], 0, 0, 0);
      acc[1][ct] = __builtin_amdgcn_mfma_f32_16x16x32_bf16(ah1, bh, acc[1][ct], 0, 0, 0);
      acc[1][ct] = __builtin_amdgcn_mfma_f32_16x16x32_bf16(al1, bh, acc[1][ct], 0, 0, 0);
    }
    __syncthreads();
  }

  if (z < 2) {
    _Float16* __restrict__ dst = (z == 0) ? qbuf : kbuf;
    const float scale = (z == 0) ? SC_Q : 1.0f;
    float bv[8];
#pragma unroll
    for (int ct = 0; ct < 8; ++ct) bv[ct] = bias[z * E_DIM + col0 + ct * 16 + lidx];
#pragma unroll
    for (int rt = 0; rt < 2; ++rt)
#pragma unroll
      for (int ct = 0; ct < 8; ++ct) {
        const int e = col0 + ct * 16 + lidx;
        const int h = e >> 6, d = e & 63;
#pragma unroll
        for (int reg = 0; reg < 4; ++reg) {
          const int R = row0 + wv * 32 + rt * 16 + quad * 4 + reg;
          const int lpos = R >> 2, nb = R & 3;
          dst[(((size_t)nb * N_HEADS + h) * L_SEQ + lpos) * H_DIM + d] =
              (_Float16)((acc[rt][ct][reg] + bv[ct]) * scale);
        }
      }
  } else {
    float bv[8], pv[8], sv[8];
#pragma unroll
    for (int ct = 0; ct < 8; ++ct) {
      const int e = col0 + ct * 16 + lidx;
      bv[ct] = bias[2 * E_DIM + e]; pv[ct] = pw[e]; sv[ct] = sw[e];
    }
#pragma unroll
    for (int rt = 0; rt < 2; ++rt)
#pragma unroll
      for (int ct = 0; ct < 8; ++ct) {
        const int e = col0 + ct * 16 + lidx;
        const int h = e >> 6, d = e & 63;
#pragma unroll
        for (int reg = 0; reg < 4; ++reg) {
          const int R = row0 + wv * 32 + rt * 16 + quad * 4 + reg;
          const int lpos = R >> 2, nb = R & 3;
          const float y = acc[rt][ct][reg] + bv[ct];
          const float vp = fmaxf(y + sv[ct], EPS_F);
          ubuf[(((size_t)nb * N_HEADS + h) * L_SEQ + lpos) * H_DIM + d] =
              __powf(vp, pv[ct]);
        }
      }
  }
}

// ---------------------------------------------------------------------------
// Kernel T: transpose u (n,h,l,d) fp32 -> u^T (n,h,d,l) fp16.
// ---------------------------------------------------------------------------
__global__ __launch_bounds__(256) void transp_kernel(
    const float* __restrict__ u, _Float16* __restrict__ uT) {
  __shared__ float T[64][65];
  const int lt = blockIdx.x, h = blockIdx.y, nb = blockIdx.z;
  const int tid = threadIdx.x;
  const int r = tid >> 2;
  const int cb = (tid & 3) * 16;
  const size_t srcbase = ((size_t)nb * N_HEADS + h) * L_SEQ + lt * 64;
  {
    const float* p = u + (srcbase + r) * H_DIM + cb;
    *(float4*)&T[r][cb + 0]  = ((const float4*)p)[0];
    *(float4*)&T[r][cb + 4]  = ((const float4*)p)[1];
    *(float4*)&T[r][cb + 8]  = ((const float4*)p)[2];
    *(float4*)&T[r][cb + 12] = ((const float4*)p)[3];
  }
  __syncthreads();
  alignas(16) _Float16 hv[16];
#pragma unroll
  for (int j = 0; j < 16; ++j) hv[j] = (_Float16)T[cb + j][r];
  const size_t dst = (((size_t)nb * N_HEADS + h) * H_DIM + r) * L_SEQ + lt * 64 + cb;
  *(uint4*)(uT + dst)     = ((const uint4*)hv)[0];
  *(uint4*)(uT + dst + 8) = ((const uint4*)hv)[1];
}

// ---------------------------------------------------------------------------
// Kernel B: fp16 MFMA flash attention, S^T orientation (A=K, B=Q) so P lives
// in registers in B-operand layout (q = lane&31): one shfl_xor(32) exchange
// replaces the LDS P round-trip.  O^T = U^T @ P^T; l = per-lane scalar sum.
//
// v6: v4/v5's register-prefetch staging failed correctness twice with an
// unexplained mechanism -- direction abandoned.  This version is v3's PROVEN
// two-barrier load-inside-window skeleton (passed, attn 113us) with ONE
// change: stage 256 s-rows per window instead of 128, as two side-by-side
// copies of v3's exact buffers (Ks0/Us0, Ks1/Us1 -- same shapes, strides,
// and per-thread access patterns).  Compute both halves per window; loop
// 16 -> 8 iterations.  This halves the count of exposed global->LDS latency
// windows and barrier drains (the measured dead time: all pipes <35%) while
// keeping v3's memory ordering verbatim.  Compute body instantiated twice
// with static buffer references (no runtime LDS indexing).  No XCD remap
// (single-variable change vs v3).  LDS 71.7 KB; 2 blocks/CU = 8 waves/CU.
// Grid (16,8,4) x 256 thr.
// ---------------------------------------------------------------------------
__global__ __launch_bounds__(256, 2) void attn_kernel(
    const _Float16* __restrict__ qbuf, const _Float16* __restrict__ kbuf,
    const _Float16* __restrict__ uT, const float* __restrict__ pw,
    const float* __restrict__ sw, __hip_bfloat16* __restrict__ ohhi,
    __hip_bfloat16* __restrict__ ohlo) {
  __shared__ union {
    struct { _Float16 Ks0[128][72]; _Float16 Us0[64][136];
             _Float16 Ks1[128][72]; _Float16 Us1[64][136]; } st;
    struct { float A[2][64][64]; float lA[2][2][64]; } red;
  } sm;
  const int qt = blockIdx.x, h = blockIdx.y, nb = blockIdx.z;
  const int q0 = qt * 128;
  const int tid = threadIdx.x;
  const int lane = tid & 63;
  const int w = tid >> 6;           // wave 0..3
  const int wv = w & 1;             // q-half of the block tile
  const int sg = w >> 1;            // s-group 0..1
  const int lm = lane & 31;
  const int kg = lane >> 5;         // k-group within MFMA operands
  const int srow = tid >> 1;        // K staging row 0..127
  const int scb = (tid & 1) * 32;   // K staging col base (fp16 units)
  const int urow = tid >> 2;        // U staging row (d) 0..63
  const int ucb = (tid & 3) * 32;   // U staging col base (s units)
  const size_t headbase = ((size_t)nb * N_HEADS + h) * L_SEQ;
  const size_t dbase = ((size_t)nb * N_HEADS + h) * H_DIM;

  // hoist Q B-frags straight from global (no Q LDS): q(nt) = q0+wv*64+nt*32+lm
  f16x8 bq[2][4];
#pragma unroll
  for (int nt = 0; nt < 2; ++nt)
#pragma unroll
    for (int kc = 0; kc < 4; ++kc)
      bq[nt][kc] = *(const f16x8*)(qbuf +
          (headbase + q0 + wv * 64 + nt * 32 + lm) * H_DIM + kc * 16 + kg * 8);

  f32x16 o[2][2];  // [q-half nt][d-half mt2]
  o[0][0] = (f32x16)(0.f); o[0][1] = (f32x16)(0.f);
  o[1][0] = (f32x16)(0.f); o[1][1] = (f32x16)(0.f);
  float lsum[2] = {0.f, 0.f};

  // compute one 64-row s-slice from a staged half-tile (v3's body verbatim)
  auto do_half = [&](const _Float16 (&Ks)[128][72], const _Float16 (&Us)[64][136]) {
    const int sr = sg * 64;  // this wave's s-rows within the staged 128

    // ---- S^T: sc[nt][mt], C-layout row = s_local, col = q (lane&31) ----
    f32x16 sc[2][2];
    sc[0][0] = (f32x16)(0.f); sc[0][1] = (f32x16)(0.f);
    sc[1][0] = (f32x16)(0.f); sc[1][1] = (f32x16)(0.f);
#pragma unroll
    for (int kc = 0; kc < 4; ++kc) {
      const f16x8 ak0 = *(const f16x8*)&Ks[sr + lm][kc * 16 + kg * 8];
      const f16x8 ak1 = *(const f16x8*)&Ks[sr + 32 + lm][kc * 16 + kg * 8];
      sc[0][0] = __builtin_amdgcn_mfma_f32_32x32x16_f16(ak0, bq[0][kc], sc[0][0], 0, 0, 0);
      sc[0][1] = __builtin_amdgcn_mfma_f32_32x32x16_f16(ak1, bq[0][kc], sc[0][1], 0, 0, 0);
      sc[1][0] = __builtin_amdgcn_mfma_f32_32x32x16_f16(ak0, bq[1][kc], sc[1][0], 0, 0, 0);
      sc[1][1] = __builtin_amdgcn_mfma_f32_32x32x16_f16(ak1, bq[1][kc], sc[1][1], 0, 0, 0);
    }

    // ---- p = exp2(score); pack fp16 pairs; per-lane l partial sum ----
    unsigned int P2[2][2][4][2];
#pragma unroll
    for (int nt = 0; nt < 2; ++nt)
#pragma unroll
      for (int mt = 0; mt < 2; ++mt)
#pragma unroll
        for (int g = 0; g < 4; ++g) {
          const float p0 = __builtin_amdgcn_exp2f(sc[nt][mt][4 * g + 0]);
          const float p1 = __builtin_amdgcn_exp2f(sc[nt][mt][4 * g + 1]);
          const float p2 = __builtin_amdgcn_exp2f(sc[nt][mt][4 * g + 2]);
          const float p3 = __builtin_amdgcn_exp2f(sc[nt][mt][4 * g + 3]);
          lsum[nt] += (p0 + p1) + (p2 + p3);
          P2[nt][mt][g][0] = packf16(p0, p1);
          P2[nt][mt][g][1] = packf16(p2, p3);
        }

    // ---- PV: O^T += U^T @ P^T; P B-frags via xor-32 exchange ----
#pragma unroll
    for (int kc = 0; kc < 4; ++kc) {
      const int mt = kc >> 1;
      const f16x8 au0 = *(const f16x8*)&Us[lm][sr + kc * 16 + kg * 8];
      const f16x8 au1 = *(const f16x8*)&Us[32 + lm][sr + kc * 16 + kg * 8];
#pragma unroll
      for (int nt = 0; nt < 2; ++nt) {
        const int gx = (2 * kc) & 3, gy = (2 * kc + 1) & 3;
        const unsigned int x0 = P2[nt][mt][gx][0], x1 = P2[nt][mt][gx][1];
        const unsigned int y0 = P2[nt][mt][gy][0], y1 = P2[nt][mt][gy][1];
        const unsigned int sA = kg ? x0 : y0, sB = kg ? x1 : y1;
        const unsigned int rA = (unsigned int)__shfl_xor((int)sA, 32);
        const unsigned int rB = (unsigned int)__shfl_xor((int)sB, 32);
        union { unsigned int u[4]; f16x8 v; } bp;
        bp.u[0] = kg ? rA : x0;  // j0..3: s = kc*16+kg*8+0..3
        bp.u[1] = kg ? rB : x1;
        bp.u[2] = kg ? y0 : rA;  // j4..7: s = kc*16+kg*8+4..7
        bp.u[3] = kg ? y1 : rB;
        o[nt][0] = __builtin_amdgcn_mfma_f32_32x32x16_f16(au0, bp.v, o[nt][0], 0, 0, 0);
        o[nt][1] = __builtin_amdgcn_mfma_f32_32x32x16_f16(au1, bp.v, o[nt][1], 0, 0, 0);
      }
    }
  };

  for (int it = 0; it < 8; ++it) {
    const int s0 = it * 256;
    __syncthreads();  // B1: prior window's frag reads complete
    {
      const _Float16* kp = kbuf + (headbase + s0 + srow) * H_DIM + scb;
      *(uint4*)&sm.st.Ks0[srow][scb + 0]  = ((const uint4*)kp)[0];
      *(uint4*)&sm.st.Ks0[srow][scb + 8]  = ((const uint4*)kp)[1];
      *(uint4*)&sm.st.Ks0[srow][scb + 16] = ((const uint4*)kp)[2];
      *(uint4*)&sm.st.Ks0[srow][scb + 24] = ((const uint4*)kp)[3];
      const _Float16* kq = kbuf + (headbase + s0 + 128 + srow) * H_DIM + scb;
      *(uint4*)&sm.st.Ks1[srow][scb + 0]  = ((const uint4*)kq)[0];
      *(uint4*)&sm.st.Ks1[srow][scb + 8]  = ((const uint4*)kq)[1];
      *(uint4*)&sm.st.Ks1[srow][scb + 16] = ((const uint4*)kq)[2];
      *(uint4*)&sm.st.Ks1[srow][scb + 24] = ((const uint4*)kq)[3];
      const _Float16* up = uT + (dbase + urow) * L_SEQ + s0 + ucb;
      *(uint4*)&sm.st.Us0[urow][ucb + 0]  = ((const uint4*)up)[0];
      *(uint4*)&sm.st.Us0[urow][ucb + 8]  = ((const uint4*)up)[1];
      *(uint4*)&sm.st.Us0[urow][ucb + 16] = ((const uint4*)up)[2];
      *(uint4*)&sm.st.Us0[urow][ucb + 24] = ((const uint4*)up)[3];
      const _Float16* uq = up + 128;
      *(uint4*)&sm.st.Us1[urow][ucb + 0]  = ((const uint4*)uq)[0];
      *(uint4*)&sm.st.Us1[urow][ucb + 8]  = ((const uint4*)uq)[1];
      *(uint4*)&sm.st.Us1[urow][ucb + 16] = ((const uint4*)uq)[2];
      *(uint4*)&sm.st.Us1[urow][ucb + 24] = ((const uint4*)uq)[3];
    }
    __syncthreads();  // B2: staged 256-row tile visible to all waves

    do_half(sm.st.Ks0, sm.st.Us0);
    do_half(sm.st.Ks1, sm.st.Us1);
  }

  // ---- cross-s-group reduction in LDS: sg1 publishes (o, lsum), sg0
  //      accumulates.  XOR-swizzled float4 slots keep accesses at the
  //      8-dwords/bank wave64 minimum (conflict-free).  ----
  float* redA = &sm.red.A[0][0][0];
  float* lrA = &sm.red.lA[0][0][0];

  __syncthreads();  // loop's trailing frag reads complete before LDS reuse
  if (sg == 1) {
#pragma unroll
    for (int nt = 0; nt < 2; ++nt) {
      lrA[(wv * 2 + nt) * 64 + lane] = lsum[nt];
#pragma unroll
      for (int mt2 = 0; mt2 < 2; ++mt2)
#pragma unroll
        for (int g = 0; g < 4; ++g) {
          const int i4 = ((nt * 2 + mt2) * 4 + g) ^ (lane & 7);
          float4 v = {o[nt][mt2][4 * g + 0], o[nt][mt2][4 * g + 1],
                      o[nt][mt2][4 * g + 2], o[nt][mt2][4 * g + 3]};
          *(float4*)(redA + ((size_t)(wv * 64 + lane)) * 64 + i4 * 4) = v;
        }
    }
  }
  __syncthreads();
  if (sg == 1) return;  // sg0 past this point; no further barriers
#pragma unroll
  for (int nt = 0; nt < 2; ++nt) {
    lsum[nt] += lrA[(wv * 2 + nt) * 64 + lane];
#pragma unroll
    for (int mt2 = 0; mt2 < 2; ++mt2)
#pragma unroll
      for (int g = 0; g < 4; ++g) {
        const int i4 = ((nt * 2 + mt2) * 4 + g) ^ (lane & 7);
        const float4 v =
            *(const float4*)(redA + ((size_t)(wv * 64 + lane)) * 64 + i4 * 4);
        o[nt][mt2][4 * g + 0] += v.x; o[nt][mt2][4 * g + 1] += v.y;
        o[nt][mt2][4 * g + 2] += v.z; o[nt][mt2][4 * g + 3] += v.w;
      }
  }

  // ---- epilogue: finish l across kg halves, GeM inverse, packed stores ----
#pragma unroll
  for (int nt = 0; nt < 2; ++nt) {
    const float l = lsum[nt] + __shfl_xor(lsum[nt], 32);
    const float inv = 1.0f / l;
    const int qg = q0 + wv * 64 + nt * 32 + lm;
    const size_t base = ((size_t)qg * N_BATCH + nb) * E_DIM + h * H_DIM;
#pragma unroll
    for (int mt2 = 0; mt2 < 2; ++mt2)
#pragma unroll
      for (int g = 0; g < 4; ++g) {
        alignas(8) __hip_bfloat16 hb[4], lb[4];
#pragma unroll
        for (int i = 0; i < 4; ++i) {
          const int d = mt2 * 32 + 8 * g + 4 * kg + i;
          const int e = h * H_DIM + d;
          const float pooled = o[nt][mt2][4 * g + i] * inv;
          const float val = __powf(fmaxf(pooled, EPS_F), 1.0f / pw[e]) - sw[e];
          split2(val, hb[i], lb[i]);
        }
        const int d0 = mt2 * 32 + 8 * g + 4 * kg;
        *(uint2*)(ohhi + base + d0) = *(const uint2*)hb;
        *(uint2*)(ohlo + base + d0) = *(const uint2*)lb;
      }
  }
}

// ---------------------------------------------------------------------------
// Kernel C: output projection via MFMA, hi/lo 3-pass.  (unchanged)
// ---------------------------------------------------------------------------
__global__ __launch_bounds__(256, 4) void out_proj_kernel(
    const __hip_bfloat16* __restrict__ xhi, const __hip_bfloat16* __restrict__ xlo,
    const __hip_bfloat16* __restrict__ whi, const __hip_bfloat16* __restrict__ wlo,
    const float* __restrict__ bias, float* __restrict__ out) {
  __shared__ __hip_bfloat16 Xh[128][40];
  __shared__ __hip_bfloat16 Xl[128][40];
  __shared__ __hip_bfloat16 Wh[64][40];
  __shared__ __hip_bfloat16 Wl[64][40];
  const int row0 = blockIdx.x * 128;
  const int col0 = blockIdx.y * 64;
  const int tid = threadIdx.x;
  const int lane = tid & 63;
  const int wv = tid >> 6;
  const int lidx = lane & 15;
  const int quad = lane >> 4;
  const int srow = tid >> 1;
  const int scol = (tid & 1) * 16;
  const int wrow = tid >> 2;
  const int wcol = (tid & 3) * 8;

  f32x4 acc[2][4];
#pragma unroll
  for (int rt = 0; rt < 2; ++rt)
#pragma unroll
    for (int ct = 0; ct < 4; ++ct) acc[rt][ct] = (f32x4){0.f, 0.f, 0.f, 0.f};

  const int ar0 = wv * 32 + lidx;

  for (int kt = 0; kt < 16; ++kt) {
    const int k0 = kt * 32;
    {
      const size_t xof = (size_t)(row0 + srow) * E_DIM + k0 + scol;
      *(uint4*)&Xh[srow][scol]     = ((const uint4*)(xhi + xof))[0];
      *(uint4*)&Xh[srow][scol + 8] = ((const uint4*)(xhi + xof))[1];
      *(uint4*)&Xl[srow][scol]     = ((const uint4*)(xlo + xof))[0];
      *(uint4*)&Xl[srow][scol + 8] = ((const uint4*)(xlo + xof))[1];
      const size_t wof = (size_t)(col0 + wrow) * E_DIM + k0 + wcol;
      *(uint4*)&Wh[wrow][wcol] = *(const uint4*)(whi + wof);
      *(uint4*)&Wl[wrow][wcol] = *(const uint4*)(wlo + wof);
    }
    __syncthreads();

    const bf16x8 ah0 = *(const bf16x8*)&Xh[ar0][quad * 8];
    const bf16x8 ah1 = *(const bf16x8*)&Xh[ar0 + 16][quad * 8];
    const bf16x8 al0 = *(const bf16x8*)&Xl[ar0][quad * 8];
    const bf16x8 al1 = *(const bf16x8*)&Xl[ar0 + 16][quad * 8];
#pragma unroll
    for (int ct = 0; ct < 4; ++ct) {
      const bf16x8 bh = *(const bf16x8*)&Wh[ct * 16 + lidx][quad * 8];
      const bf16x8 bl = *(const bf16x8*)&Wl[ct * 16 + lidx][quad * 8];
      acc[0][ct] = __builtin_amdgcn_mfma_f32_16x16x32_bf16(ah0, bh, acc[0][ct], 0, 0, 0);
      acc[0][ct] = __builtin_amdgcn_mfma_f32_16x16x32_bf16(al0, bh, acc[0][ct], 0, 0, 0);
      acc[0][ct] = __builtin_amdgcn_mfma_f32_16x16x32_bf16(ah0, bl, acc[0][ct], 0, 0, 0);
      acc[1][ct] = __builtin_amdgcn_mfma_f32_16x16x32_bf16(ah1, bh, acc[1][ct], 0, 0, 0);
      acc[1][ct] = __builtin_amdgcn_mfma_f32_16x16x32_bf16(al1, bh, acc[1][ct], 0, 0, 0);
      acc[1][ct] = __builtin_amdgcn_mfma_f32_16x16x32_bf16(ah1, bl, acc[1][ct], 0, 0, 0);
    }
    __syncthreads();
  }

  float bv[4];
#pragma unroll
  for (int ct = 0; ct < 4; ++ct) bv[ct] = bias[col0 + ct * 16 + lidx];
#pragma unroll
  for (int rt = 0; rt < 2; ++rt)
#pragma unroll
    for (int ct = 0; ct < 4; ++ct) {
      const int c = col0 + ct * 16 + lidx;
#pragma unroll
      for (int reg = 0; reg < 4; ++reg) {
        const int R = row0 + wv * 32 + rt * 16 + quad * 4 + reg;
        out[(size_t)R * E_DIM + c] = acc[rt][ct][reg] + bv[ct];
      }
    }
}

extern "C" void kernel_launch(void* const* d_in, const int* in_sizes, int n_in,
                              void* d_out, int out_size, void* d_ws, size_t ws_size,
                              hipStream_t stream) {
  const float* q_in = (const float*)d_in[0];
  const float* k_in = (const float*)d_in[1];
  const float* v_in = (const float*)d_in[2];
  const float* wio  = (const float*)d_in[3];
  const float* bio  = (const float*)d_in[4];
  const float* wo   = (const float*)d_in[5];
  const float* bo   = (const float*)d_in[6];
  const float* pw   = (const float*)d_in[7];
  const float* sw   = (const float*)d_in[8];

  // Workspace: qbuf,kbuf f16 (8 MiB ea); ubuf fp32 16 MiB (reused as
  // ohhi/ohlo bf16 8+8 after transp); uT f16 8 MiB; weight splits ~4 MiB.
  const size_t NE = (size_t)N_ROWS * E_DIM;
  _Float16* qbuf = (_Float16*)d_ws;
  _Float16* kbuf = qbuf + NE;
  float* ubuf = (float*)(kbuf + NE);
  _Float16* uT = (_Float16*)(ubuf + NE);
  __hip_bfloat16* wiohi = (__hip_bfloat16*)(uT + NE);
  __hip_bfloat16* wiolo = wiohi + 786432;
  __hip_bfloat16* wohi  = wiolo + 786432;
  __hip_bfloat16* wolo  = wohi + 262144;
  __hip_bfloat16* ohhi = (__hip_bfloat16*)ubuf;  // alias: ubuf dead after transp
  __hip_bfloat16* ohlo = ohhi + NE;

  wconv_kernel<<<dim3(1024), 256, 0, stream>>>(wio, wo, wiohi, wiolo, wohi, wolo);
  proj_qkv_kernel<<<dim3(64, 4, 3), 256, 0, stream>>>(q_in, k_in, v_in, wiohi,
                                                      bio, pw, sw, qbuf, kbuf, ubuf);
  transp_kernel<<<dim3(32, 8, 4), 256, 0, stream>>>(ubuf, uT);
  attn_kernel<<<dim3(16, 8, 4), 256, 0, stream>>>(qbuf, kbuf, uT, pw, sw,
                                                  ohhi, ohlo);
  out_proj_kernel<<<dim3(64, 8), 256, 0, stream>>>(ohhi, ohlo, wohi, wolo,
                                                   bo, (float*)d_out);
}